// Round 1
// baseline (4676.414 us; speedup 1.0000x reference)
//
#include <hip/hip_runtime.h>

#define B_   2048   // batch
#define H_   512    // hidden
#define I_   128    // input size
#define G4   2048   // 4*H
#define SEQ  100
#define DEC  29
#define OUT_ 128

typedef __attribute__((ext_vector_type(8))) short bf16x8;
typedef __attribute__((ext_vector_type(4))) float f32x4;

__device__ inline unsigned short f2bf(float f) {
    union { float f; unsigned int u; } v; v.f = f;
    unsigned int u = v.u + 0x7fffu + ((v.u >> 16) & 1u);
    return (unsigned short)(u >> 16);
}
__device__ inline float sigm(float x)  { return 1.f / (1.f + __expf(-x)); }
__device__ inline float tanh_(float x) { return 2.f / (1.f + __expf(-2.f * x)) - 1.f; }

// One LSTM step: gates = h @ Whᵀ (+ x @ Wxᵀ) + bias, then elementwise cell update.
// Wave tile: 32 rows x 16 hidden cols; computes all 4 gates for its cols so the
// nonlinearity is in-register. Block = 4 waves (32 rows x 64 hidden cols).
// grid = (B/32, H/64). h is ping-ponged (cross-block read hazard); c in-place.
__global__ __launch_bounds__(256) void lstm_step(
    const unsigned short* __restrict__ hin,   // [B_, H_] bf16
    const unsigned short* __restrict__ Wh,    // [G4, H_] bf16
    const unsigned short* __restrict__ Wx,    // [G4, I_] bf16 or null
    const float*          __restrict__ x,     // [B_, I_] fp32 or null
    const float*          __restrict__ bias,  // [G4]
    float*                __restrict__ c,     // [B_, H_] fp32 state (in-place)
    unsigned short*       __restrict__ hout,  // [B_, H_] bf16
    float*                __restrict__ houtf, // optional fp32 h dump
    float*                __restrict__ coutf) // optional fp32 c dump
{
    const int lane = threadIdx.x & 63;
    const int wv   = threadIdx.x >> 6;
    const int quad = lane >> 4;
    const int l16  = lane & 15;
    const int m0   = blockIdx.x * 32;
    const int col  = blockIdx.y * 64 + wv * 16 + l16;   // hidden column

    f32x4 acc[2][4];
#pragma unroll
    for (int r = 0; r < 2; ++r)
#pragma unroll
        for (int g = 0; g < 4; ++g) acc[r][g] = (f32x4){0.f, 0.f, 0.f, 0.f};

    // A fragment rows (A[m=lane&15][k=quad*8+j])
    const unsigned short* a0p = hin + (size_t)(m0 + l16) * H_ + quad * 8;
    const unsigned short* a1p = a0p + 16 * H_;

    for (int k = 0; k < H_; k += 32) {
        bf16x8 a0 = *(const bf16x8*)(a0p + k);
        bf16x8 a1 = *(const bf16x8*)(a1p + k);
#pragma unroll
        for (int g = 0; g < 4; ++g) {
            bf16x8 b = *(const bf16x8*)(Wh + (size_t)(g * H_ + col) * H_ + k + quad * 8);
            acc[0][g] = __builtin_amdgcn_mfma_f32_16x16x32_bf16(a0, b, acc[0][g], 0, 0, 0);
            acc[1][g] = __builtin_amdgcn_mfma_f32_16x16x32_bf16(a1, b, acc[1][g], 0, 0, 0);
        }
    }

    if (x) {  // encoder: fold x @ Wxᵀ with on-the-fly fp32->bf16 of x
        for (int k = 0; k < I_; k += 32) {
            const float* p0 = x + (size_t)(m0 + l16) * I_ + k + quad * 8;
            const float* p1 = p0 + 16 * I_;
            float4 f0a = *(const float4*)(p0);
            float4 f0b = *(const float4*)(p0 + 4);
            float4 f1a = *(const float4*)(p1);
            float4 f1b = *(const float4*)(p1 + 4);
            bf16x8 a0, a1;
            a0[0] = (short)f2bf(f0a.x); a0[1] = (short)f2bf(f0a.y);
            a0[2] = (short)f2bf(f0a.z); a0[3] = (short)f2bf(f0a.w);
            a0[4] = (short)f2bf(f0b.x); a0[5] = (short)f2bf(f0b.y);
            a0[6] = (short)f2bf(f0b.z); a0[7] = (short)f2bf(f0b.w);
            a1[0] = (short)f2bf(f1a.x); a1[1] = (short)f2bf(f1a.y);
            a1[2] = (short)f2bf(f1a.z); a1[3] = (short)f2bf(f1a.w);
            a1[4] = (short)f2bf(f1b.x); a1[5] = (short)f2bf(f1b.y);
            a1[6] = (short)f2bf(f1b.z); a1[7] = (short)f2bf(f1b.w);
#pragma unroll
            for (int g = 0; g < 4; ++g) {
                bf16x8 b = *(const bf16x8*)(Wx + (size_t)(g * H_ + col) * I_ + k + quad * 8);
                acc[0][g] = __builtin_amdgcn_mfma_f32_16x16x32_bf16(a0, b, acc[0][g], 0, 0, 0);
                acc[1][g] = __builtin_amdgcn_mfma_f32_16x16x32_bf16(a1, b, acc[1][g], 0, 0, 0);
            }
        }
    }

    // Epilogue: torch gate order i,f,g,o at column offsets {0,1,2,3}*H_
    const float b0 = bias[col];
    const float b1 = bias[H_ + col];
    const float b2 = bias[2 * H_ + col];
    const float b3 = bias[3 * H_ + col];
#pragma unroll
    for (int r = 0; r < 2; ++r) {
#pragma unroll
        for (int j = 0; j < 4; ++j) {
            // C/D layout: row = quad*4 + j, col = lane&15   [m89-verified]
            int row = m0 + r * 16 + quad * 4 + j;
            size_t idx = (size_t)row * H_ + col;
            float gi = acc[r][0][j] + b0;
            float gf = acc[r][1][j] + b1;
            float gg = acc[r][2][j] + b2;
            float go = acc[r][3][j] + b3;
            float ii = sigm(gi);
            float ff = sigm(gf);
            float g2 = tanh_(gg);
            float oo = sigm(go);
            float cn = ff * c[idx] + ii * g2;
            c[idx] = cn;
            float hn = oo * tanh_(cn);
            hout[idx] = (unsigned short)f2bf(hn);
            if (houtf) houtf[idx] = hn;
            if (coutf) coutf[idx] = cn;
        }
    }
}

// out = h @ W_linᵀ + b_lin : [B_,512] x [128,512]ᵀ -> [B_,128]
// Wave: 64 rows x 16 cols. Block = 4 waves (64 x 64). grid = (B/64, OUT/64).
__global__ __launch_bounds__(256) void out_gemm(
    const unsigned short* __restrict__ h,    // [B_, H_] bf16
    const unsigned short* __restrict__ Wl,   // [OUT_, H_] bf16
    const float*          __restrict__ bl,   // [OUT_]
    float*                __restrict__ out)  // [B_, OUT_]
{
    const int lane = threadIdx.x & 63;
    const int wv   = threadIdx.x >> 6;
    const int quad = lane >> 4;
    const int l16  = lane & 15;
    const int m0   = blockIdx.x * 64;
    const int col  = blockIdx.y * 64 + wv * 16 + l16;

    f32x4 acc[4];
#pragma unroll
    for (int r = 0; r < 4; ++r) acc[r] = (f32x4){0.f, 0.f, 0.f, 0.f};

    for (int k = 0; k < H_; k += 32) {
        bf16x8 b = *(const bf16x8*)(Wl + (size_t)col * H_ + k + quad * 8);
#pragma unroll
        for (int r = 0; r < 4; ++r) {
            bf16x8 a = *(const bf16x8*)(h + (size_t)(m0 + r * 16 + l16) * H_ + k + quad * 8);
            acc[r] = __builtin_amdgcn_mfma_f32_16x16x32_bf16(a, b, acc[r], 0, 0, 0);
        }
    }
    const float bb = bl[col];
#pragma unroll
    for (int r = 0; r < 4; ++r)
#pragma unroll
        for (int j = 0; j < 4; ++j)
            out[(size_t)(m0 + r * 16 + quad * 4 + j) * OUT_ + col] = acc[r][j] + bb;
}

// Weight prep: fp32 -> bf16; decoder weights/biases pre-combined (x == h).
__global__ void prep(const float* __restrict__ whh_e, const float* __restrict__ wih_e,
                     const float* __restrict__ wih_d, const float* __restrict__ whh_d,
                     const float* __restrict__ wlin,
                     const float* __restrict__ bie, const float* __restrict__ bhe,
                     const float* __restrict__ bid, const float* __restrict__ bhd,
                     unsigned short* __restrict__ Whe, unsigned short* __restrict__ Wie,
                     unsigned short* __restrict__ Wd,  unsigned short* __restrict__ Wl,
                     float* __restrict__ be, float* __restrict__ bd)
{
    int i = blockIdx.x * blockDim.x + threadIdx.x;
    if (i < G4 * H_) {
        Whe[i] = f2bf(whh_e[i]);
        Wd[i]  = f2bf(wih_d[i] + whh_d[i]);
    }
    if (i < G4 * I_)  Wie[i] = f2bf(wih_e[i]);
    if (i < OUT_ * H_) Wl[i] = f2bf(wlin[i]);
    if (i < G4) { be[i] = bie[i] + bhe[i]; bd[i] = bid[i] + bhd[i]; }
}

__global__ void init_state(const float* __restrict__ h0, const float* __restrict__ c0,
                           unsigned short* __restrict__ hb, float* __restrict__ c)
{
    int i = blockIdx.x * blockDim.x + threadIdx.x;
    if (i < B_ * H_) { hb[i] = f2bf(h0[i]); c[i] = c0[i]; }
}

__global__ void set_c(const float* __restrict__ c0, float* __restrict__ c)
{
    int i = blockIdx.x * blockDim.x + threadIdx.x;
    if (i < B_ * H_) c[i] = c0[i];
}

extern "C" void kernel_launch(void* const* d_in, const int* in_sizes, int n_in,
                              void* d_out, int out_size, void* d_ws, size_t ws_size,
                              hipStream_t stream) {
    (void)in_sizes; (void)n_in; (void)out_size; (void)ws_size;
    const float* input  = (const float*)d_in[0];
    const float* h_enc0 = (const float*)d_in[1];
    // d_in[2] hidden_decoder is unused by the reference
    const float* c_enc0 = (const float*)d_in[3];
    const float* c_dec0 = (const float*)d_in[4];
    const float* Wih_e  = (const float*)d_in[5];
    const float* Whh_e  = (const float*)d_in[6];
    const float* bih_e  = (const float*)d_in[7];
    const float* bhh_e  = (const float*)d_in[8];
    const float* Wih_d  = (const float*)d_in[9];
    const float* Whh_d  = (const float*)d_in[10];
    const float* bih_d  = (const float*)d_in[11];
    const float* bhh_d  = (const float*)d_in[12];
    const float* Wlin   = (const float*)d_in[13];
    const float* blin   = (const float*)d_in[14];
    float* out = (float*)d_out;

    char* ws = (char*)d_ws;
    size_t off = 0;
    auto alloc = [&](size_t bytes) -> void* {
        void* p = ws + off;
        off = (off + bytes + 255) & ~(size_t)255;
        return p;
    };
    unsigned short* Whe = (unsigned short*)alloc((size_t)G4 * H_ * 2);
    unsigned short* Wie = (unsigned short*)alloc((size_t)G4 * I_ * 2);
    unsigned short* Wd  = (unsigned short*)alloc((size_t)G4 * H_ * 2);
    unsigned short* Wl  = (unsigned short*)alloc((size_t)OUT_ * H_ * 2);
    float* be = (float*)alloc((size_t)G4 * 4);
    float* bd = (float*)alloc((size_t)G4 * 4);
    unsigned short* hA = (unsigned short*)alloc((size_t)B_ * H_ * 2);
    unsigned short* hB = (unsigned short*)alloc((size_t)B_ * H_ * 2);
    float* c = (float*)alloc((size_t)B_ * H_ * 4);

    float* out_y    = out;                                   // [30, B_, OUT_]
    float* out_hEnc = out + (size_t)30 * B_ * OUT_;
    float* out_hDec = out_hEnc + (size_t)B_ * H_;
    float* out_cEnc = out_hDec + (size_t)B_ * H_;
    float* out_cDec = out_cEnc + (size_t)B_ * H_;

    prep<<<(G4 * H_ + 255) / 256, 256, 0, stream>>>(
        Whh_e, Wih_e, Wih_d, Whh_d, Wlin, bih_e, bhh_e, bih_d, bhh_d,
        Whe, Wie, Wd, Wl, be, bd);
    init_state<<<(B_ * H_ + 255) / 256, 256, 0, stream>>>(h_enc0, c_enc0, hA, c);

    dim3 sgrid(B_ / 32, H_ / 64);
    dim3 ogrid(B_ / 64, OUT_ / 64);
    unsigned short* cur = hA;
    unsigned short* nxt = hB;

    for (int t = 0; t < SEQ; ++t) {
        bool last = (t == SEQ - 1);
        lstm_step<<<sgrid, 256, 0, stream>>>(
            cur, Whe, Wie, input + (size_t)t * B_ * I_, be, c, nxt,
            last ? out_hEnc : nullptr, last ? out_cEnc : nullptr);
        unsigned short* tmp = cur; cur = nxt; nxt = tmp;
    }

    // hs[0] = h_enc
    out_gemm<<<ogrid, 256, 0, stream>>>(cur, Wl, blin, out_y);
    // decoder cell starts from cell_decoder input
    set_c<<<(B_ * H_ + 255) / 256, 256, 0, stream>>>(c_dec0, c);

    for (int s = 0; s < DEC; ++s) {
        bool last = (s == DEC - 1);
        lstm_step<<<sgrid, 256, 0, stream>>>(
            cur, Wd, nullptr, nullptr, bd, c, nxt,
            last ? out_hDec : nullptr, last ? out_cDec : nullptr);
        unsigned short* tmp = cur; cur = nxt; nxt = tmp;
        out_gemm<<<ogrid, 256, 0, stream>>>(cur, Wl, blin, out_y + (size_t)(s + 1) * B_ * OUT_);
    }
}

// Round 2
// 2254.521 us; speedup vs baseline: 2.0742x; 2.0742x over previous
//
#include <hip/hip_runtime.h>

#define B_   2048   // batch
#define H_   512    // hidden
#define I_   128    // input size
#define G4   2048   // 4*H
#define SEQ  100
#define DEC  29
#define OUT_ 128

typedef __attribute__((ext_vector_type(8))) short bf16x8;
typedef __attribute__((ext_vector_type(4))) float f32x4;
typedef __attribute__((address_space(3))) unsigned int       lds_u32;
typedef __attribute__((address_space(1))) const unsigned int glb_u32c;

__device__ inline unsigned short f2bf(float f) {
    union { float f; unsigned int u; } v; v.f = f;
    unsigned int u = v.u + 0x7fffu + ((v.u >> 16) & 1u);
    return (unsigned short)(u >> 16);
}
__device__ inline float sigm(float x)  { return 1.f / (1.f + __expf(-x)); }
__device__ inline float tanh_(float x) { return 2.f / (1.f + __expf(-2.f * x)) - 1.f; }

__device__ inline void gload16(const unsigned short* g, unsigned short* l) {
    __builtin_amdgcn_global_load_lds((glb_u32c*)g, (lds_u32*)l, 16, 0, 0);
}

// One LSTM step, LDS-tiled. gates = [h | x] @ Wcat^T + bias, then cell update.
// Block: 512 thr (8 waves). Tile: M=128 rows x 32 hidden cols x 4 gates.
// Waves: w_m = w>>1 (4 row groups of 32), w_n = w&1 (2 col groups of 16).
// grid = (B_/128, H_/32) = (16,16) = 256 blocks = 1/CU.
// LDS: A tile [128 rows][64 k] 16 KB + B tile [128 W-rows][64 k] 16 KB,
// staged via global_load_lds w16; seg XOR-swizzle (seg^=row&7) keeps
// ds_read_b128 at 2-way bank aliasing (free) instead of 16-way.
__global__ __launch_bounds__(512, 2) void lstm_step(
    const unsigned short* __restrict__ hin,   // [B_, H_] bf16
    const unsigned short* __restrict__ xb,    // [B_, I_] bf16 or null (decoder)
    const unsigned short* __restrict__ W,     // [G4, Kw] bf16
    const int Kw,                             // 640 (enc) or 512 (dec)
    const float*          __restrict__ bias,  // [G4]
    float*                __restrict__ c,     // [B_, H_] fp32, in-place
    unsigned short*       __restrict__ hout,  // [B_, H_] bf16
    float*                __restrict__ houtf, // optional fp32 h dump
    float*                __restrict__ coutf) // optional fp32 c dump
{
    __shared__ unsigned short smem[16384];    // 32 KB: A [0,8192), B [8192,16384) elems

    const int tid  = threadIdx.x;
    const int lane = tid & 63;
    const int w    = tid >> 6;     // 0..7
    const int quad = lane >> 4;
    const int l16  = lane & 15;
    const int w_m  = w >> 1;       // 0..3
    const int w_n  = w & 1;        // 0..1
    const int m0   = blockIdx.x * 128;
    const int c0   = blockIdx.y * 32;

    // staging: lane lands at LDS base + lane*16; seg XOR-swizzle per lane
    const int segl = (lane & 7) ^ ((lane >> 3) & 7);

    const unsigned short* gb[4];
    const unsigned short* gbx[4];
    unsigned short* lb[4];
    const bool isA = (w < 4);
    if (isA) {
        const int rbase = w * 32 + (lane >> 3);
#pragma unroll
        for (int i = 0; i < 4; ++i) {
            const int row = rbase + i * 8;
            gb[i]  = hin + (size_t)(m0 + row) * H_ + segl * 8;
            gbx[i] = xb ? (xb + (size_t)(m0 + row) * I_ + segl * 8) : hin;
            lb[i]  = smem + w * 2048 + i * 512;          // 4 KB/wave, 1 KB/instr
        }
    } else {
        const int w2 = w - 4;
        const int rbase = w2 * 32 + (lane >> 3);
#pragma unroll
        for (int i = 0; i < 4; ++i) {
            const int rowN = rbase + i * 8;              // 0..127 = g*32 + j
            const int g = rowN >> 5, j = rowN & 31;
            gb[i] = W + (size_t)(g * H_ + c0 + j) * Kw + segl * 8;
            lb[i] = smem + 8192 + w2 * 2048 + i * 512;
        }
    }

    // ds_read byte offsets (constant across chunks)
    int offA[2][2], offB[4][2];
#pragma unroll
    for (int rf = 0; rf < 2; ++rf)
#pragma unroll
        for (int ks = 0; ks < 2; ++ks) {
            const int row = w_m * 32 + rf * 16 + l16;
            const int seg = ks * 4 + quad;
            offA[rf][ks] = row * 128 + ((seg ^ (row & 7)) * 16);
        }
#pragma unroll
    for (int g = 0; g < 4; ++g)
#pragma unroll
        for (int ks = 0; ks < 2; ++ks) {
            const int row = g * 32 + w_n * 16 + l16;
            const int seg = ks * 4 + quad;
            offB[g][ks] = 16384 + row * 128 + ((seg ^ (row & 7)) * 16);
        }

    f32x4 acc[2][4];
#pragma unroll
    for (int rf = 0; rf < 2; ++rf)
#pragma unroll
        for (int g = 0; g < 4; ++g) acc[rf][g] = (f32x4){0.f, 0.f, 0.f, 0.f};

    const int kcH = H_ / 64;     // 8 chunks from h
    const int kcN = Kw / 64;     // 8 (dec) or 10 (enc)
    const char* sbase = (const char*)smem;

    for (int kc = 0; kc < kcN; ++kc) {
        if (isA) {
            if (kc < kcH) {
#pragma unroll
                for (int i = 0; i < 4; ++i) gload16(gb[i] + kc * 64, lb[i]);
            } else {
#pragma unroll
                for (int i = 0; i < 4; ++i) gload16(gbx[i] + (kc - kcH) * 64, lb[i]);
            }
        } else {
#pragma unroll
            for (int i = 0; i < 4; ++i) gload16(gb[i] + kc * 64, lb[i]);
        }
        __syncthreads();
#pragma unroll
        for (int ks = 0; ks < 2; ++ks) {
            bf16x8 a0 = *(const bf16x8*)(sbase + offA[0][ks]);
            bf16x8 a1 = *(const bf16x8*)(sbase + offA[1][ks]);
#pragma unroll
            for (int g = 0; g < 4; ++g) {
                bf16x8 b = *(const bf16x8*)(sbase + offB[g][ks]);
                acc[0][g] = __builtin_amdgcn_mfma_f32_16x16x32_bf16(a0, b, acc[0][g], 0, 0, 0);
                acc[1][g] = __builtin_amdgcn_mfma_f32_16x16x32_bf16(a1, b, acc[1][g], 0, 0, 0);
            }
        }
        __syncthreads();
    }

    // Epilogue: torch gate order i,f,g,o at W row offsets {0,1,2,3}*H_
    const int col = c0 + w_n * 16 + l16;
    const float b0 = bias[col];
    const float b1 = bias[H_ + col];
    const float b2 = bias[2 * H_ + col];
    const float b3 = bias[3 * H_ + col];
#pragma unroll
    for (int rf = 0; rf < 2; ++rf) {
#pragma unroll
        for (int j = 0; j < 4; ++j) {
            // C/D layout: row = quad*4 + j, col = lane&15   [m89-verified]
            const int row = m0 + w_m * 32 + rf * 16 + quad * 4 + j;
            const size_t idx = (size_t)row * H_ + col;
            const float gi = acc[rf][0][j] + b0;
            const float gf = acc[rf][1][j] + b1;
            const float gg = acc[rf][2][j] + b2;
            const float go = acc[rf][3][j] + b3;
            const float ii = sigm(gi);
            const float ff = sigm(gf);
            const float g2 = tanh_(gg);
            const float oo = sigm(go);
            const float cn = ff * c[idx] + ii * g2;
            c[idx] = cn;
            const float hn = oo * tanh_(cn);
            hout[idx] = (unsigned short)f2bf(hn);
            if (houtf) houtf[idx] = hn;
            if (coutf) coutf[idx] = cn;
        }
    }
}

// out = hs @ W_linᵀ + b_lin : [M,512] x [128,512]ᵀ -> [M,128], M = 30*B_
// Wave: 64 rows x 16 cols. Block = 4 waves (64 x 64). grid = (M/64, OUT/64).
__global__ __launch_bounds__(256) void out_gemm(
    const unsigned short* __restrict__ h,    // [M, H_] bf16
    const unsigned short* __restrict__ Wl,   // [OUT_, H_] bf16
    const float*          __restrict__ bl,   // [OUT_]
    float*                __restrict__ out)  // [M, OUT_]
{
    const int lane = threadIdx.x & 63;
    const int wv   = threadIdx.x >> 6;
    const int quad = lane >> 4;
    const int l16  = lane & 15;
    const int m0   = blockIdx.x * 64;
    const int col  = blockIdx.y * 64 + wv * 16 + l16;

    f32x4 acc[4];
#pragma unroll
    for (int r = 0; r < 4; ++r) acc[r] = (f32x4){0.f, 0.f, 0.f, 0.f};

    for (int k = 0; k < H_; k += 32) {
        bf16x8 b = *(const bf16x8*)(Wl + (size_t)col * H_ + k + quad * 8);
#pragma unroll
        for (int r = 0; r < 4; ++r) {
            bf16x8 a = *(const bf16x8*)(h + (size_t)(m0 + r * 16 + l16) * H_ + k + quad * 8);
            acc[r] = __builtin_amdgcn_mfma_f32_16x16x32_bf16(a, b, acc[r], 0, 0, 0);
        }
    }
    const float bb = bl[col];
#pragma unroll
    for (int r = 0; r < 4; ++r)
#pragma unroll
        for (int j = 0; j < 4; ++j)
            out[(size_t)(m0 + r * 16 + quad * 4 + j) * OUT_ + col] = acc[r][j] + bb;
}

// Weight prep: Wcat_e[r][k] = k<512 ? Whh_e[r][k] : Wih_e[r][k-512] (bf16);
// Wd = bf16(Wih_d + Whh_d) (decoder input IS h); Wl = bf16(W_lin); biases combined.
__global__ void prep(const float* __restrict__ whh_e, const float* __restrict__ wih_e,
                     const float* __restrict__ wih_d, const float* __restrict__ whh_d,
                     const float* __restrict__ wlin,
                     const float* __restrict__ bie, const float* __restrict__ bhe,
                     const float* __restrict__ bid, const float* __restrict__ bhd,
                     unsigned short* __restrict__ Wce, unsigned short* __restrict__ Wd,
                     unsigned short* __restrict__ Wl,
                     float* __restrict__ be, float* __restrict__ bd)
{
    const int i = blockIdx.x * blockDim.x + threadIdx.x;
    if (i < G4 * 640) {
        const int r = i / 640, k = i % 640;
        Wce[i] = f2bf(k < H_ ? whh_e[r * H_ + k] : wih_e[r * I_ + (k - H_)]);
    }
    if (i < G4 * H_)   Wd[i] = f2bf(wih_d[i] + whh_d[i]);
    if (i < OUT_ * H_) Wl[i] = f2bf(wlin[i]);
    if (i < G4) { be[i] = bie[i] + bhe[i]; bd[i] = bid[i] + bhd[i]; }
}

// fp32 -> bf16 conversion of the whole input sequence (SEQ*B_*I_ elements)
__global__ void xconv(const float* __restrict__ x, unsigned short* __restrict__ xb, int n4)
{
    const int i = blockIdx.x * blockDim.x + threadIdx.x;
    if (i < n4) {
        const float4 f = *(const float4*)(x + (size_t)i * 4);
        ushort4 o;
        o.x = f2bf(f.x); o.y = f2bf(f.y); o.z = f2bf(f.z); o.w = f2bf(f.w);
        *(ushort4*)(xb + (size_t)i * 4) = o;
    }
}

__global__ void init_state(const float* __restrict__ h0, const float* __restrict__ c0,
                           unsigned short* __restrict__ hb, float* __restrict__ c)
{
    const int i = blockIdx.x * blockDim.x + threadIdx.x;
    if (i < B_ * H_) { hb[i] = f2bf(h0[i]); c[i] = c0[i]; }
}

__global__ void set_c(const float* __restrict__ c0, float* __restrict__ c)
{
    const int i = blockIdx.x * blockDim.x + threadIdx.x;
    if (i < B_ * H_) c[i] = c0[i];
}

extern "C" void kernel_launch(void* const* d_in, const int* in_sizes, int n_in,
                              void* d_out, int out_size, void* d_ws, size_t ws_size,
                              hipStream_t stream) {
    (void)in_sizes; (void)n_in; (void)out_size; (void)ws_size;
    const float* input  = (const float*)d_in[0];
    const float* h_enc0 = (const float*)d_in[1];
    // d_in[2] hidden_decoder is unused by the reference
    const float* c_enc0 = (const float*)d_in[3];
    const float* c_dec0 = (const float*)d_in[4];
    const float* Wih_e  = (const float*)d_in[5];
    const float* Whh_e  = (const float*)d_in[6];
    const float* bih_e  = (const float*)d_in[7];
    const float* bhh_e  = (const float*)d_in[8];
    const float* Wih_d  = (const float*)d_in[9];
    const float* Whh_d  = (const float*)d_in[10];
    const float* bih_d  = (const float*)d_in[11];
    const float* bhh_d  = (const float*)d_in[12];
    const float* Wlin   = (const float*)d_in[13];
    const float* blin   = (const float*)d_in[14];
    float* out = (float*)d_out;

    char* ws = (char*)d_ws;
    size_t off = 0;
    auto alloc = [&](size_t bytes) -> void* {
        void* p = ws + off;
        off = (off + bytes + 255) & ~(size_t)255;
        return p;
    };
    unsigned short* Wce = (unsigned short*)alloc((size_t)G4 * 640 * 2);
    unsigned short* Wd  = (unsigned short*)alloc((size_t)G4 * H_ * 2);
    unsigned short* Wl  = (unsigned short*)alloc((size_t)OUT_ * H_ * 2);
    float* be = (float*)alloc((size_t)G4 * 4);
    float* bd = (float*)alloc((size_t)G4 * 4);
    unsigned short* hA  = (unsigned short*)alloc((size_t)B_ * H_ * 2);
    unsigned short* hB  = (unsigned short*)alloc((size_t)B_ * H_ * 2);
    float* c            = (float*)alloc((size_t)B_ * H_ * 4);
    unsigned short* xbf = (unsigned short*)alloc((size_t)SEQ * B_ * I_ * 2);
    unsigned short* hs  = (unsigned short*)alloc((size_t)(DEC + 1) * B_ * H_ * 2);

    float* out_y    = out;                                   // [30, B_, OUT_]
    float* out_hEnc = out + (size_t)(DEC + 1) * B_ * OUT_;
    float* out_hDec = out_hEnc + (size_t)B_ * H_;
    float* out_cEnc = out_hDec + (size_t)B_ * H_;
    float* out_cDec = out_cEnc + (size_t)B_ * H_;

    prep<<<(G4 * 640 + 255) / 256, 256, 0, stream>>>(
        Whh_e, Wih_e, Wih_d, Whh_d, Wlin, bih_e, bhh_e, bih_d, bhh_d,
        Wce, Wd, Wl, be, bd);
    xconv<<<(SEQ * B_ * I_ / 4 + 255) / 256, 256, 0, stream>>>(input, xbf, SEQ * B_ * I_ / 4);
    init_state<<<(B_ * H_ + 255) / 256, 256, 0, stream>>>(h_enc0, c_enc0, hA, c);

    dim3 sgrid(B_ / 128, H_ / 32);          // (16,16) = 256 blocks
    unsigned short* cur = hA;
    unsigned short* nxt = hB;

    for (int t = 0; t < SEQ; ++t) {
        const bool last = (t == SEQ - 1);
        unsigned short* dst = last ? hs : nxt;   // hs[0] = h_enc
        lstm_step<<<sgrid, 512, 0, stream>>>(
            cur, xbf + (size_t)t * B_ * I_, Wce, 640, be, c, dst,
            last ? out_hEnc : nullptr, last ? out_cEnc : nullptr);
        unsigned short* tmp = cur; cur = nxt; nxt = tmp;
    }

    set_c<<<(B_ * H_ + 255) / 256, 256, 0, stream>>>(c_dec0, c);

    for (int s = 0; s < DEC; ++s) {
        const bool last = (s == DEC - 1);
        lstm_step<<<sgrid, 512, 0, stream>>>(
            hs + (size_t)s * B_ * H_, nullptr, Wd, 512, bd, c,
            hs + (size_t)(s + 1) * B_ * H_,
            last ? out_hDec : nullptr, last ? out_cDec : nullptr);
    }

    // One batched output GEMM over all 30 h states
    dim3 ogrid((DEC + 1) * B_ / 64, OUT_ / 64);
    out_gemm<<<ogrid, 256, 0, stream>>>(hs, Wl, blin, out_y);
}